// Round 2
// baseline (626.499 us; speedup 1.0000x reference)
//
#include <hip/hip_runtime.h>
#include <math.h>

#define NA 3
#define NM 32
#define NC 80
#define STRIDE_PX 8.0f
#define THRESH 0.05f
#define NB 16
#define NH 80
#define NW 80
#define NHW (NH * NW)                 // 6400
#define CH (NA * (5 + NC) + NA * NM)  // 351
#define BOXCH (NA * (5 + NC))         // 255
#define TOTAL (NB * NA * NHW)         // 307200
#define BLK 256
#define NBLK (TOTAL / BLK)            // 1200
#define ROWSZ (7 + NM)                // 39

#define FLAG_AGG  (1u << 30)
#define FLAG_PREF (2u << 30)
#define VAL_MASK  ((1u << 30) - 1u)

// Single fused kernel: decode + softmax + score, then order-preserving stream
// compaction via decoupled-lookback prefix (rocPRIM-style), then row write +
// mask-coefficient gather. All per-candidate values stay in registers.
__global__ __launch_bounds__(BLK) void fused_kernel(
    const float* __restrict__ in, const float* __restrict__ anchors,
    float* __restrict__ out, int out_size, unsigned int* __restrict__ flags) {
  int g = blockIdx.x * BLK + threadIdx.x;
  int p = g % NHW;
  int a = (g / NHW) % NA;
  int b = g / (NA * NHW);

  const float* base = in + ((size_t)b * CH + (size_t)a * (5 + NC)) * NHW + p;

  float tx = base[0];
  float ty = base[(size_t)1 * NHW];
  float tw = base[(size_t)2 * NHW];
  float th = base[(size_t)3 * NHW];
  float tobj = base[(size_t)4 * NHW];

  // class logits in registers; two-pass softmax (bit-identical to round 1)
  float cl[NC];
  float m = -INFINITY;
  int idx = 0;
#pragma unroll
  for (int j = 0; j < NC; ++j) {
    cl[j] = base[(size_t)(5 + j) * NHW];
    if (cl[j] > m) { m = cl[j]; idx = j; }  // strict > => first occurrence
  }
  float s = 0.f;
#pragma unroll
  for (int j = 0; j < NC; ++j) s += expf(cl[j] - m);

  float cls_max = 1.0f / s;
  float obj = 1.0f / (1.0f + expf(-tobj));
  float score = cls_max * obj;

  float amax = fmaxf(fmaxf(fmaxf(anchors[0], anchors[1]), fmaxf(anchors[2], anchors[3])),
                     fmaxf(anchors[4], anchors[5]));
  float max_value = floorf(logf(1e35f / amax / STRIDE_PX));
  float aw = anchors[a * 2 + 0];
  float ah = anchors[a * 2 + 1];

  float xs = 1.0f / (1.0f + expf(-tx)) + (float)(p % NW);
  float ys = 1.0f / (1.0f + expf(-ty)) + (float)(p / NW);
  float w = expf(fminf(tw, max_value)) * aw;
  float h = expf(fminf(th, max_value)) * ah;

  // ---- block-local rank ----
  bool keep = score > THRESH;
  unsigned long long ball = __ballot(keep);
  int lane = threadIdx.x & 63;
  int wv = threadIdx.x >> 6;
  int lower = __popcll(ball & ((1ull << lane) - 1ull));
  __shared__ int wc[BLK / 64];
  __shared__ int s_off;
  if (lane == 0) wc[wv] = __popcll(ball);
  __syncthreads();
  int pre = 0;
#pragma unroll
  for (int i = 0; i < BLK / 64; ++i)
    if (i < wv) pre += wc[i];

  // ---- decoupled lookback: exclusive prefix of block keep-counts ----
  if (threadIdx.x == 0) {
    unsigned agg = (unsigned)(wc[0] + wc[1] + wc[2] + wc[3]);
    unsigned bid = blockIdx.x;
    if (bid == 0) {
      __hip_atomic_store(&flags[0], FLAG_PREF | agg, __ATOMIC_RELEASE,
                         __HIP_MEMORY_SCOPE_AGENT);
      s_off = 0;
    } else {
      __hip_atomic_store(&flags[bid], FLAG_AGG | agg, __ATOMIC_RELEASE,
                         __HIP_MEMORY_SCOPE_AGENT);
      unsigned run = 0;
      int j = (int)bid - 1;
      while (true) {
        unsigned f = __hip_atomic_load(&flags[j], __ATOMIC_ACQUIRE,
                                       __HIP_MEMORY_SCOPE_AGENT);
        if (f & FLAG_PREF) { run += f & VAL_MASK; break; }
        if (f & FLAG_AGG)  { run += f & VAL_MASK; --j; }
        // else: predecessor not published yet — spin
      }
      __hip_atomic_store(&flags[bid], FLAG_PREF | (run + agg), __ATOMIC_RELEASE,
                         __HIP_MEMORY_SCOPE_AGENT);
      s_off = (int)run;
    }
  }
  __syncthreads();
  int row0 = s_off;

  // ---- compacted write + mask-coefficient gather ----
  if (keep) {
    int row = row0 + pre + lower;
    if ((size_t)(row + 1) * ROWSZ <= (size_t)out_size) {
      float* o = out + (size_t)row * ROWSZ;
      o[0] = (float)b;
      o[1] = xs * STRIDE_PX;
      o[2] = ys * STRIDE_PX;
      o[3] = w * STRIDE_PX;
      o[4] = h * STRIDE_PX;
      const float* mbase = in + ((size_t)b * CH + BOXCH + (size_t)a * NM) * NHW + p;
#pragma unroll
      for (int mm = 0; mm < NM; ++mm) o[5 + mm] = mbase[(size_t)mm * NHW];
      o[5 + NM] = score;        // 37
      o[6 + NM] = (float)idx;   // 38
    }
  }
}

extern "C" void kernel_launch(void* const* d_in, const int* in_sizes, int n_in,
                              void* d_out, int out_size, void* d_ws, size_t ws_size,
                              hipStream_t stream) {
  const float* in = (const float*)d_in[0];
  const float* anchors = (const float*)d_in[1];

  unsigned int* flags = (unsigned int*)d_ws;  // NBLK u32, must start at 0

  hipMemsetAsync(flags, 0, NBLK * sizeof(unsigned int), stream);
  fused_kernel<<<NBLK, BLK, 0, stream>>>(in, anchors, (float*)d_out, out_size, flags);
}

// Round 3
// 372.362 us; speedup vs baseline: 1.6825x; 1.6825x over previous
//
#include <hip/hip_runtime.h>
#include <math.h>

#define NA 3
#define NM 32
#define NC 80
#define STRIDE_PX 8.0f
#define THRESH 0.05f
#define NB 16
#define NH 80
#define NW 80
#define NHW (NH * NW)                 // 6400
#define CH (NA * (5 + NC) + NA * NM)  // 351
#define BOXCH (NA * (5 + NC))         // 255
#define TOTAL (NB * NA * NHW)         // 307200
#define BLK 256
#define NBLK (TOTAL / BLK)            // 1200
#define ROWSZ (7 + NM)                // 39

#define FLAG_AGG  (1u << 30)
#define FLAG_PREF (2u << 30)
#define FLAG_ANY  (3u << 30)
#define VAL_MASK  ((1u << 30) - 1u)

__device__ __forceinline__ int wave_sum64(int v) {
#pragma unroll
  for (int s = 32; s > 0; s >>= 1) v += __shfl_xor(v, s, 64);
  return v;
}

// Single fused kernel: decode + softmax + score, order-preserving compaction
// via decoupled lookback with WAVE-PARALLEL window scan (round-2 scalar walk
// was 1199 serial L2-atomic loads => 482us of spin).
__global__ __launch_bounds__(BLK) void fused_kernel(
    const float* __restrict__ in, const float* __restrict__ anchors,
    float* __restrict__ out, int out_size, unsigned int* __restrict__ flags) {
  int g = blockIdx.x * BLK + threadIdx.x;
  int p = g % NHW;
  int a = (g / NHW) % NA;
  int b = g / (NA * NHW);

  const float* base = in + ((size_t)b * CH + (size_t)a * (5 + NC)) * NHW + p;

  float tx = base[0];
  float ty = base[(size_t)1 * NHW];
  float tw = base[(size_t)2 * NHW];
  float th = base[(size_t)3 * NHW];
  float tobj = base[(size_t)4 * NHW];

  // class logits in registers; two-pass softmax (bit-identical to round 1)
  float cl[NC];
  float m = -INFINITY;
  int idx = 0;
#pragma unroll
  for (int j = 0; j < NC; ++j) {
    cl[j] = base[(size_t)(5 + j) * NHW];
    if (cl[j] > m) { m = cl[j]; idx = j; }  // strict > => first occurrence
  }
  float s = 0.f;
#pragma unroll
  for (int j = 0; j < NC; ++j) s += expf(cl[j] - m);

  float cls_max = 1.0f / s;
  float obj = 1.0f / (1.0f + expf(-tobj));
  float score = cls_max * obj;

  float amax = fmaxf(fmaxf(fmaxf(anchors[0], anchors[1]), fmaxf(anchors[2], anchors[3])),
                     fmaxf(anchors[4], anchors[5]));
  float max_value = floorf(logf(1e35f / amax / STRIDE_PX));
  float aw = anchors[a * 2 + 0];
  float ah = anchors[a * 2 + 1];

  float xs = 1.0f / (1.0f + expf(-tx)) + (float)(p % NW);
  float ys = 1.0f / (1.0f + expf(-ty)) + (float)(p / NW);
  float w = expf(fminf(tw, max_value)) * aw;
  float h = expf(fminf(th, max_value)) * ah;

  // ---- block-local rank ----
  bool keep = score > THRESH;
  unsigned long long ball = __ballot(keep);
  int lane = threadIdx.x & 63;
  int wv = threadIdx.x >> 6;
  int lower = __popcll(ball & ((1ull << lane) - 1ull));
  __shared__ int wc[BLK / 64];
  __shared__ int s_off;
  if (lane == 0) wc[wv] = __popcll(ball);
  __syncthreads();
  int pre = 0;
#pragma unroll
  for (int i = 0; i < BLK / 64; ++i)
    if (i < wv) pre += wc[i];

  // ---- decoupled lookback, wave 0, 64-wide windows ----
  if (wv == 0) {
    const int bid = (int)blockIdx.x;
    const unsigned agg = (unsigned)(wc[0] + wc[1] + wc[2] + wc[3]);
    if (lane == 0) {
      unsigned v0 = (bid == 0) ? (FLAG_PREF | agg) : (FLAG_AGG | agg);
      __hip_atomic_store(&flags[bid], v0, __ATOMIC_RELEASE, __HIP_MEMORY_SCOPE_AGENT);
    }
    int run = 0;
    if (bid > 0) {
      int wend = bid;  // window is [wend-64, wend-1]
      for (;;) {
        int j = wend - 64 + lane;
        unsigned f = (j >= 0)
            ? __hip_atomic_load(&flags[j], __ATOMIC_ACQUIRE, __HIP_MEMORY_SCOPE_AGENT)
            : (FLAG_PREF | 0u);
        unsigned long long prefm = __ballot((f & FLAG_PREF) != 0u);
        unsigned long long notrdy = __ballot((f & FLAG_ANY) == 0u);
        if (prefm != 0ull) {
          int hi = 63 - __clzll(prefm);  // highest lane holding a PREF
          unsigned long long above = (hi < 63) ? (~0ull << (hi + 1)) : 0ull;
          if ((notrdy & above) == 0ull) {
            int contrib = (lane >= hi) ? (int)(f & VAL_MASK) : 0;
            run += wave_sum64(contrib);
            break;
          }
        } else if (notrdy == 0ull) {
          run += wave_sum64((int)(f & VAL_MASK));  // whole window is AGG
          wend -= 64;
        }
        // otherwise: retry this window
      }
      if (lane == 0)
        __hip_atomic_store(&flags[bid], FLAG_PREF | ((unsigned)run + agg),
                           __ATOMIC_RELEASE, __HIP_MEMORY_SCOPE_AGENT);
    }
    if (lane == 0) s_off = run;
  }
  __syncthreads();
  int row0 = s_off;

  // ---- compacted write + mask-coefficient gather ----
  if (keep) {
    int row = row0 + pre + lower;
    if ((size_t)(row + 1) * ROWSZ <= (size_t)out_size) {
      float* o = out + (size_t)row * ROWSZ;
      o[0] = (float)b;
      o[1] = xs * STRIDE_PX;
      o[2] = ys * STRIDE_PX;
      o[3] = w * STRIDE_PX;
      o[4] = h * STRIDE_PX;
      const float* mbase = in + ((size_t)b * CH + BOXCH + (size_t)a * NM) * NHW + p;
#pragma unroll
      for (int mm = 0; mm < NM; ++mm) o[5 + mm] = mbase[(size_t)mm * NHW];
      o[5 + NM] = score;        // 37
      o[6 + NM] = (float)idx;   // 38
    }
  }
}

extern "C" void kernel_launch(void* const* d_in, const int* in_sizes, int n_in,
                              void* d_out, int out_size, void* d_ws, size_t ws_size,
                              hipStream_t stream) {
  const float* in = (const float*)d_in[0];
  const float* anchors = (const float*)d_in[1];

  unsigned int* flags = (unsigned int*)d_ws;  // NBLK u32, must start at 0

  hipMemsetAsync(flags, 0, NBLK * sizeof(unsigned int), stream);
  fused_kernel<<<NBLK, BLK, 0, stream>>>(in, anchors, (float*)d_out, out_size, flags);
}

// Round 4
// 225.187 us; speedup vs baseline: 2.7821x; 1.6536x over previous
//
#include <hip/hip_runtime.h>
#include <math.h>

#define NA 3
#define NM 32
#define NC 80
#define STRIDE_PX 8.0f
#define THRESH 0.05f
#define NB 16
#define NH 80
#define NW 80
#define NHW (NH * NW)                 // 6400
#define CH (NA * (5 + NC) + NA * NM)  // 351
#define BOXCH (NA * (5 + NC))         // 255
#define TOTAL (NB * NA * NHW)         // 307200
#define BLK 256
#define NBLK (TOTAL / BLK)            // 1200
#define ROWSZ (7 + NM)                // 39
#define WS_ROW_STRIDE (BLK * ROWSZ)   // 9984 floats per block's row slab

__device__ __forceinline__ int wave_sum64(int v) {
#pragma unroll
  for (int s = 32; s > 0; s >>= 1) v += __shfl_xor(v, s, 64);
  return v;
}

// ---- Kernel A: decode + online softmax + score; block-local compaction into ws ----
// Online softmax (running max/sum) avoids the cl[80] array -> no scratch spill.
// __expf = v_exp_f32: argmax is exact (compares raw logits); score error ~1e-7 rel.
__global__ __launch_bounds__(BLK) void decode_kernel(
    const float* __restrict__ in, const float* __restrict__ anchors,
    float* __restrict__ wsrows, int* __restrict__ counts) {
  int g = blockIdx.x * BLK + threadIdx.x;
  int p = g % NHW;
  int a = (g / NHW) % NA;
  int b = g / (NA * NHW);

  const float* base = in + ((size_t)b * CH + (size_t)a * (5 + NC)) * NHW + p;

  float tx = base[0];
  float ty = base[(size_t)1 * NHW];
  float tw = base[(size_t)2 * NHW];
  float th = base[(size_t)3 * NHW];
  float tobj = base[(size_t)4 * NHW];

  // online softmax + first-occurrence argmax (strict >), branch-free
  float m = -INFINITY, s = 0.f;
  int idx = 0;
#pragma unroll
  for (int j = 0; j < NC; ++j) {
    float x = base[(size_t)(5 + j) * NHW];
    float mn = fmaxf(m, x);
    s = s * __expf(m - mn) + __expf(x - mn);
    idx = (x > m) ? j : idx;
    m = mn;
  }

  float cls_max = 1.0f / s;
  float obj = 1.0f / (1.0f + __expf(-tobj));
  float score = cls_max * obj;

  float amax = fmaxf(fmaxf(fmaxf(anchors[0], anchors[1]), fmaxf(anchors[2], anchors[3])),
                     fmaxf(anchors[4], anchors[5]));
  float max_value = floorf(logf(1e35f / amax / STRIDE_PX));
  float aw = anchors[a * 2 + 0];
  float ah = anchors[a * 2 + 1];

  float xs = 1.0f / (1.0f + __expf(-tx)) + (float)(p % NW);
  float ys = 1.0f / (1.0f + __expf(-ty)) + (float)(p / NW);
  float w = __expf(fminf(tw, max_value)) * aw;
  float h = __expf(fminf(th, max_value)) * ah;

  // block-local rank (thread order == global (b,a,p) order)
  bool keep = score > THRESH;
  unsigned long long ball = __ballot(keep);
  int lane = threadIdx.x & 63;
  int wv = threadIdx.x >> 6;
  int lower = __popcll(ball & ((1ull << lane) - 1ull));
  __shared__ int wc[BLK / 64];
  if (lane == 0) wc[wv] = __popcll(ball);
  __syncthreads();
  int pre = 0;
#pragma unroll
  for (int i = 0; i < BLK / 64; ++i)
    if (i < wv) pre += wc[i];

  if (keep) {
    int lrank = pre + lower;
    float* o = wsrows + (size_t)blockIdx.x * WS_ROW_STRIDE + (size_t)lrank * ROWSZ;
    o[0] = (float)b;
    o[1] = xs * STRIDE_PX;
    o[2] = ys * STRIDE_PX;
    o[3] = w * STRIDE_PX;
    o[4] = h * STRIDE_PX;
    const float* mbase = in + ((size_t)b * CH + BOXCH + (size_t)a * NM) * NHW + p;
#pragma unroll
    for (int mm = 0; mm < NM; ++mm) o[5 + mm] = mbase[(size_t)mm * NHW];
    o[5 + NM] = score;
    o[6 + NM] = (float)idx;
  }
  if (threadIdx.x == 0)
    counts[blockIdx.x] = wc[0] + wc[1] + wc[2] + wc[3];
}

// ---- Kernel B: per-block redundant prefix over 1200 counts + dense linear copy ----
__global__ __launch_bounds__(BLK) void emit_kernel(
    const float* __restrict__ wsrows, const int* __restrict__ counts,
    float* __restrict__ out, int out_size) {
  int bid = blockIdx.x;
  int t = threadIdx.x;

  int partial = 0;
  for (int j = t; j < bid; j += BLK) partial += counts[j];
  partial = wave_sum64(partial);
  __shared__ int sh[BLK / 64];
  if ((t & 63) == 0) sh[t >> 6] = partial;
  __syncthreads();
  int off = sh[0] + sh[1] + sh[2] + sh[3];

  int cnt = counts[bid];
  int nelem = cnt * ROWSZ;
  const float* src = wsrows + (size_t)bid * WS_ROW_STRIDE;
  int dbase = off * ROWSZ;
  for (int e = t; e < nelem; e += BLK) {
    int d = dbase + e;
    if (d < out_size) out[d] = src[e];
  }
}

extern "C" void kernel_launch(void* const* d_in, const int* in_sizes, int n_in,
                              void* d_out, int out_size, void* d_ws, size_t ws_size,
                              hipStream_t stream) {
  const float* in = (const float*)d_in[0];
  const float* anchors = (const float*)d_in[1];

  float* wsrows = (float*)d_ws;                              // NBLK * 9984 floats (~48 MB)
  int* counts = (int*)((float*)d_ws + (size_t)NBLK * WS_ROW_STRIDE);

  decode_kernel<<<NBLK, BLK, 0, stream>>>(in, anchors, wsrows, counts);
  emit_kernel<<<NBLK, BLK, 0, stream>>>(wsrows, counts, (float*)d_out, out_size);
}